// Round 1
// baseline (1132.070 us; speedup 1.0000x reference)
//
#include <hip/hip_runtime.h>
#include <cstdint>

// ---------------------------------------------------------------------------
// DirGraphSAGE: 3 layers of {fwd-agg, bwd-agg, concat-GEMM(+bias,+relu)}
// Strategy round 0: correctness-first full pipeline.
//   - Build CSR for both edge directions once per launch (degrees -> scan -> fill)
//   - Gather-based aggregation (no fp32 atomics in hot loop), one wave per node
//   - LDS-tiled fp32 GEMM fused over the 3 concat sources + bias + relu
// ---------------------------------------------------------------------------

__global__ __launch_bounds__(256) void k_degrees(const int* __restrict__ src,
                                                 const int* __restrict__ dst,
                                                 int* __restrict__ cnt_in,
                                                 int* __restrict__ cnt_out, int E) {
  int e = blockIdx.x * 256 + threadIdx.x;
  if (e >= E) return;
  atomicAdd(&cnt_out[src[e]], 1);
  atomicAdd(&cnt_in[dst[e]], 1);
}

__global__ __launch_bounds__(256) void k_inv(const int* __restrict__ cnt_in,
                                             const int* __restrict__ cnt_out,
                                             float* __restrict__ inv_in,
                                             float* __restrict__ inv_out, int n) {
  int i = blockIdx.x * 256 + threadIdx.x;
  if (i >= n) return;
  inv_out[i] = 1.0f / (float)max(cnt_out[i], 1);
  inv_in[i]  = 1.0f / (float)max(cnt_in[i], 1);
}

// Single-block exclusive scan over n counts -> off[0..n] (off[n] = total).
__global__ __launch_bounds__(1024) void k_scan(const int* __restrict__ cnt,
                                               int* __restrict__ off, int n) {
  __shared__ int part[1024];
  int t = threadIdx.x;
  int CH = (n + 1023) / 1024;
  int base = t * CH;
  int s = 0;
  for (int i = 0; i < CH; ++i) { int idx = base + i; if (idx < n) s += cnt[idx]; }
  part[t] = s;
  __syncthreads();
  for (int o = 1; o < 1024; o <<= 1) {
    int v = (t >= o) ? part[t - o] : 0;
    __syncthreads();
    part[t] += v;
    __syncthreads();
  }
  int run = (t == 0) ? 0 : part[t - 1];
  for (int i = 0; i < CH; ++i) {
    int idx = base + i;
    if (idx < n) { off[idx] = run; run += cnt[idx]; }
  }
  if (t == 1023) off[n] = part[1023];
}

__global__ __launch_bounds__(256) void k_fill(const int* __restrict__ src,
                                              const int* __restrict__ dst,
                                              const int* __restrict__ offf,
                                              const int* __restrict__ offb,
                                              int* __restrict__ curf,
                                              int* __restrict__ curb,
                                              int* __restrict__ lstf,
                                              int* __restrict__ lstb, int E) {
  int e = blockIdx.x * 256 + threadIdx.x;
  if (e >= E) return;
  int s = src[e], d = dst[e];
  int pf = offf[d] + atomicAdd(&curf[d], 1);
  lstf[pf] = s;                                  // fwd: grouped by dst, holds src
  int pb = offb[s] + atomicAdd(&curb[s], 1);
  lstb[pb] = d;                                  // bwd: grouped by src, holds dst
}

// One wave per node: out[v,:] = sum_{u in list(v)} x[u,:] * inv[u]
__global__ __launch_bounds__(256) void k_agg(const float* __restrict__ x,
                                             const int* __restrict__ off,
                                             const int* __restrict__ lst,
                                             const float* __restrict__ inv,
                                             float* __restrict__ out, int n) {
  int wave = (blockIdx.x * 256 + threadIdx.x) >> 6;
  int lane = threadIdx.x & 63;
  if (wave >= n) return;
  int beg = off[wave], end = off[wave + 1];
  const float2* x2 = (const float2*)x;
  float2 acc = make_float2(0.f, 0.f);
  int i = beg;
  for (; i + 1 < end; i += 2) {
    int u0 = lst[i], u1 = lst[i + 1];
    float w0 = inv[u0], w1 = inv[u1];
    float2 a = x2[(size_t)u0 * 64 + lane];
    float2 b = x2[(size_t)u1 * 64 + lane];
    acc.x += a.x * w0; acc.y += a.y * w0;
    acc.x += b.x * w1; acc.y += b.y * w1;
  }
  if (i < end) {
    int u = lst[i];
    float w = inv[u];
    float2 a = x2[(size_t)u * 64 + lane];
    acc.x += a.x * w; acc.y += a.y * w;
  }
  ((float2*)out)[(size_t)wave * 64 + lane] = acc;
}

// out[v,j] = (relu?) bias[j] + sum_k xcur[v,k]W[k,j] + fwd[v,k]W[128+k,j] + bwd[v,k]W[256+k,j]
// BM=64 nodes/block, 256 threads, each thread 4 rows x 8 cols.
// Safe in-place (out == xcur): each block only reads the rows it writes, and all
// staging reads of xcur happen before the epilogue stores.
__global__ __launch_bounds__(256) void k_gemm(const float* __restrict__ xcur,
                                              const float* __restrict__ fwdb,
                                              const float* __restrict__ bwdb,
                                              const float* __restrict__ W,
                                              const float* __restrict__ bias,
                                              float* __restrict__ out, int n, int relu) {
  __shared__ __align__(16) float sW[64 * 128];   // 32 KB: W rows [kc*64, kc*64+64)
  __shared__ __align__(16) float sH[64 * 68];    // 17.4 KB: 64 nodes x 64 k, pad 68
  int tid = threadIdx.x;
  int bm0 = blockIdx.x * 64;
  int tc = tid & 15, tr = tid >> 4;
  int j0 = tc * 8, m0 = tr * 4;
  float acc[4][8];
#pragma unroll
  for (int r = 0; r < 4; ++r)
#pragma unroll
    for (int c = 0; c < 8; ++c) acc[r][c] = 0.f;

  for (int kc = 0; kc < 6; ++kc) {
    const float* hsrc = (kc < 2) ? xcur : ((kc < 4) ? fwdb : bwdb);
    int k0 = (kc & 1) * 64;
    __syncthreads();
    const float4* Wg = (const float4*)(W + kc * 64 * 128);
    float4* sW4 = (float4*)sW;
#pragma unroll
    for (int p = 0; p < 8; ++p) sW4[tid + p * 256] = Wg[tid + p * 256];
    const float4* Hg = (const float4*)hsrc;
    float4* sH4 = (float4*)sH;
#pragma unroll
    for (int p = 0; p < 4; ++p) {
      int f = tid + p * 256;
      int row = f >> 4, c4 = f & 15;
      int v = bm0 + row;
      float4 val = make_float4(0.f, 0.f, 0.f, 0.f);
      if (v < n) val = Hg[(size_t)v * 32 + (k0 >> 2) + c4];
      sH4[row * 17 + c4] = val;
    }
    __syncthreads();
#pragma unroll 8
    for (int kk = 0; kk < 64; ++kk) {
      float4 w0 = *(const float4*)&sW[kk * 128 + j0];
      float4 w1 = *(const float4*)&sW[kk * 128 + j0 + 4];
      float hv[4];
      hv[0] = sH[(m0 + 0) * 68 + kk];
      hv[1] = sH[(m0 + 1) * 68 + kk];
      hv[2] = sH[(m0 + 2) * 68 + kk];
      hv[3] = sH[(m0 + 3) * 68 + kk];
      float wv[8] = {w0.x, w0.y, w0.z, w0.w, w1.x, w1.y, w1.z, w1.w};
#pragma unroll
      for (int r = 0; r < 4; ++r)
#pragma unroll
        for (int c = 0; c < 8; ++c) acc[r][c] += hv[r] * wv[c];
    }
  }

  float bj[8];
#pragma unroll
  for (int c = 0; c < 8; ++c) bj[c] = bias[j0 + c];
#pragma unroll
  for (int r = 0; r < 4; ++r) {
    int v = bm0 + m0 + r;
    if (v >= n) continue;
    float o[8];
#pragma unroll
    for (int c = 0; c < 8; ++c) {
      float t = acc[r][c] + bj[c];
      o[c] = relu ? fmaxf(t, 0.f) : t;
    }
    float4* op = (float4*)(out + (size_t)v * 128 + j0);
    op[0] = make_float4(o[0], o[1], o[2], o[3]);
    op[1] = make_float4(o[4], o[5], o[6], o[7]);
  }
}

extern "C" void kernel_launch(void* const* d_in, const int* in_sizes, int n_in,
                              void* d_out, int out_size, void* d_ws, size_t ws_size,
                              hipStream_t stream) {
  const int D = 128;
  const int N = in_sizes[0] / D;
  const int E = in_sizes[7];

  const float* x  = (const float*)d_in[0];
  const float* W0 = (const float*)d_in[1];
  const float* b0 = (const float*)d_in[2];
  const float* W1 = (const float*)d_in[3];
  const float* b1 = (const float*)d_in[4];
  const float* W2 = (const float*)d_in[5];
  const float* b2 = (const float*)d_in[6];
  const int* src  = (const int*)d_in[7];
  const int* dst  = (const int*)d_in[8];
  float* out = (float*)d_out;

  // workspace layout
  char* p = (char*)d_ws;
  float* invout = (float*)p; p += (size_t)N * 4;
  float* invin  = (float*)p; p += (size_t)N * 4;
  int* cntin  = (int*)p;     p += (size_t)N * 4;
  int* cntout = (int*)p;     p += (size_t)N * 4;
  int* offf = (int*)p;       p += (size_t)(N + 1) * 4;
  int* offb = (int*)p;       p += (size_t)(N + 1) * 4;
  int* curf = (int*)p;       p += (size_t)N * 4;
  int* curb = (int*)p;       p += (size_t)N * 4;
  int* lstf = (int*)p;       p += (size_t)E * 4;
  int* lstb = (int*)p;       p += (size_t)E * 4;
  p = (char*)(((uintptr_t)p + 15) & ~(uintptr_t)15);
  float* fwdb = (float*)p;   p += (size_t)N * D * 4;
  float* bwdb = (float*)p;   p += (size_t)N * D * 4;
  float* x1   = (float*)p;   p += (size_t)N * D * 4;

  hipMemsetAsync(cntin, 0, (size_t)2 * N * 4, stream);  // cntin + cntout contiguous
  hipMemsetAsync(curf,  0, (size_t)2 * N * 4, stream);  // curf + curb contiguous

  k_degrees<<<(E + 255) / 256, 256, 0, stream>>>(src, dst, cntin, cntout, E);
  k_inv<<<(N + 255) / 256, 256, 0, stream>>>(cntin, cntout, invin, invout, N);
  k_scan<<<1, 1024, 0, stream>>>(cntin, offf, N);
  k_scan<<<1, 1024, 0, stream>>>(cntout, offb, N);
  k_fill<<<(E + 255) / 256, 256, 0, stream>>>(src, dst, offf, offb, curf, curb,
                                              lstf, lstb, E);

  const float* Ws[3] = {W0, W1, W2};
  const float* bs[3] = {b0, b1, b2};
  int aggBlocks = (N * 64 + 255) / 256;  // one wave per node
  for (int l = 0; l < 3; ++l) {
    const float* xc = (l == 0) ? x : ((l == 1) ? x1 : out);
    float* xo = (l == 0) ? x1 : out;
    // fwd[v] = sum_{s: (s,v) edge} x[s] * inv_out[s]
    k_agg<<<aggBlocks, 256, 0, stream>>>(xc, offf, lstf, invout, fwdb, N);
    // bwd[v] = sum_{d: (v,d) edge} x[d] * inv_in[d]
    k_agg<<<aggBlocks, 256, 0, stream>>>(xc, offb, lstb, invin, bwdb, N);
    k_gemm<<<(N + 63) / 64, 256, 0, stream>>>(xc, fwdb, bwdb, Ws[l], bs[l], xo, N,
                                              (l < 2) ? 1 : 0);
  }
}

// Round 2
// 917.269 us; speedup vs baseline: 1.2342x; 1.2342x over previous
//
#include <hip/hip_runtime.h>
#include <cstdint>

// ---------------------------------------------------------------------------
// DirGraphSAGE round 1:
//  - rank-trick CSR build (atomic rank captured in degree pass; fill is
//    atomic-free scatter)
//  - aggregation gathers PRE-SCALED bf16 rows (x*inv rounded RNE once per
//    layer) -> halves gather bytes, shrinks gather footprint to 12.8 MB
//  - agg outputs stored bf16; GEMM stages them to fp32 LDS on load
//  - GEMM math stays fp32 (accuracy headroom), candidate for MFMA next round
// ---------------------------------------------------------------------------

__device__ __forceinline__ unsigned short f2bf(float f) {
  unsigned u = __float_as_uint(f);
  u += 0x7FFFu + ((u >> 16) & 1u);   // round-to-nearest-even
  return (unsigned short)(u >> 16);
}
__device__ __forceinline__ float bflo(unsigned u) { return __uint_as_float(u << 16); }
__device__ __forceinline__ float bfhi(unsigned u) { return __uint_as_float(u & 0xFFFF0000u); }

__global__ __launch_bounds__(256) void k_degrees(const int* __restrict__ src,
                                                 const int* __restrict__ dst,
                                                 int* __restrict__ cnt_in,
                                                 int* __restrict__ cnt_out,
                                                 int* __restrict__ rankf,
                                                 int* __restrict__ rankb, int E) {
  int e = blockIdx.x * 256 + threadIdx.x;
  if (e >= E) return;
  int s = src[e], d = dst[e];
  rankf[e] = atomicAdd(&cnt_in[d], 1);   // rank within fwd list (grouped by dst)
  rankb[e] = atomicAdd(&cnt_out[s], 1);  // rank within bwd list (grouped by src)
}

__global__ __launch_bounds__(256) void k_inv(const int* __restrict__ cnt_in,
                                             const int* __restrict__ cnt_out,
                                             float* __restrict__ inv_in,
                                             float* __restrict__ inv_out, int n) {
  int i = blockIdx.x * 256 + threadIdx.x;
  if (i >= n) return;
  inv_out[i] = 1.0f / (float)max(cnt_out[i], 1);
  inv_in[i]  = 1.0f / (float)max(cnt_in[i], 1);
}

// Single-block exclusive scan over n counts -> off[0..n] (off[n] = total).
__global__ __launch_bounds__(1024) void k_scan(const int* __restrict__ cnt,
                                               int* __restrict__ off, int n) {
  __shared__ int part[1024];
  int t = threadIdx.x;
  int CH = (n + 1023) / 1024;
  int base = t * CH;
  int s = 0;
  for (int i = 0; i < CH; ++i) { int idx = base + i; if (idx < n) s += cnt[idx]; }
  part[t] = s;
  __syncthreads();
  for (int o = 1; o < 1024; o <<= 1) {
    int v = (t >= o) ? part[t - o] : 0;
    __syncthreads();
    part[t] += v;
    __syncthreads();
  }
  int run = (t == 0) ? 0 : part[t - 1];
  for (int i = 0; i < CH; ++i) {
    int idx = base + i;
    if (idx < n) { off[idx] = run; run += cnt[idx]; }
  }
  if (t == 1023) off[n] = part[1023];
}

// Atomic-free fill using precomputed ranks.
__global__ __launch_bounds__(256) void k_fill(const int* __restrict__ src,
                                              const int* __restrict__ dst,
                                              const int* __restrict__ offf,
                                              const int* __restrict__ offb,
                                              const int* __restrict__ rankf,
                                              const int* __restrict__ rankb,
                                              int* __restrict__ lstf,
                                              int* __restrict__ lstb, int E) {
  int e = blockIdx.x * 256 + threadIdx.x;
  if (e >= E) return;
  int s = src[e], d = dst[e];
  lstf[offf[d] + rankf[e]] = s;   // fwd: grouped by dst, holds src
  lstb[offb[s] + rankb[e]] = d;   // bwd: grouped by src, holds dst
}

// x (fp32, N x 128) -> xbo = bf16(x*inv_out), xbi = bf16(x*inv_in)
// One thread per 4 floats (= 2 packed bf16x2 uints out per array).
__global__ __launch_bounds__(256) void k_conv(const float* __restrict__ x,
                                              const float* __restrict__ inv_out,
                                              const float* __restrict__ inv_in,
                                              unsigned* __restrict__ xbo,
                                              unsigned* __restrict__ xbi, int n) {
  int idx = blockIdx.x * 256 + threadIdx.x;  // over n*32 float4s
  if (idx >= n * 32) return;
  int v = idx >> 5;
  float so = inv_out[v], si = inv_in[v];
  float4 xv = ((const float4*)x)[idx];
  unsigned o0 = (unsigned)f2bf(xv.x * so) | ((unsigned)f2bf(xv.y * so) << 16);
  unsigned o1 = (unsigned)f2bf(xv.z * so) | ((unsigned)f2bf(xv.w * so) << 16);
  ((uint2*)xbo)[idx] = make_uint2(o0, o1);
  unsigned i0 = (unsigned)f2bf(xv.x * si) | ((unsigned)f2bf(xv.y * si) << 16);
  unsigned i1 = (unsigned)f2bf(xv.z * si) | ((unsigned)f2bf(xv.w * si) << 16);
  ((uint2*)xbi)[idx] = make_uint2(i0, i1);
}

// One wave per node: outb[v,:] = bf16( sum_{u in list(v)} xb[u,:] )
// xb rows are pre-scaled bf16 (128 cols = 64 packed uints; lane holds 1 uint).
__global__ __launch_bounds__(256) void k_agg(const unsigned* __restrict__ xb,
                                             const int* __restrict__ off,
                                             const int* __restrict__ lst,
                                             unsigned* __restrict__ outb, int n) {
  int wave = (blockIdx.x * 256 + threadIdx.x) >> 6;
  int lane = threadIdx.x & 63;
  if (wave >= n) return;
  int beg = off[wave], end = off[wave + 1];
  float ax = 0.f, ay = 0.f;
  int i = beg;
  for (; i + 3 < end; i += 4) {
    int u0 = lst[i], u1 = lst[i + 1], u2 = lst[i + 2], u3 = lst[i + 3];
    unsigned a = xb[(size_t)u0 * 64 + lane];
    unsigned b = xb[(size_t)u1 * 64 + lane];
    unsigned c = xb[(size_t)u2 * 64 + lane];
    unsigned d = xb[(size_t)u3 * 64 + lane];
    ax += bflo(a); ay += bfhi(a);
    ax += bflo(b); ay += bfhi(b);
    ax += bflo(c); ay += bfhi(c);
    ax += bflo(d); ay += bfhi(d);
  }
  for (; i < end; ++i) {
    unsigned a = xb[(size_t)lst[i] * 64 + lane];
    ax += bflo(a); ay += bfhi(a);
  }
  outb[(size_t)wave * 64 + lane] = (unsigned)f2bf(ax) | ((unsigned)f2bf(ay) << 16);
}

// out[v,j] = (relu?) bias[j] + sum_k xcur[v,k]W[k,j] + fwd[v,k]W[128+k,j] + bwd[v,k]W[256+k,j]
// xcur fp32; fwdb/bwdb packed bf16x2. BM=64 nodes/block, 256 threads,
// each thread 4 rows x 8 cols. In-place safe (block reads only its own rows).
__global__ __launch_bounds__(256) void k_gemm(const float* __restrict__ xcur,
                                              const unsigned* __restrict__ fwdb,
                                              const unsigned* __restrict__ bwdb,
                                              const float* __restrict__ W,
                                              const float* __restrict__ bias,
                                              float* __restrict__ out, int n, int relu) {
  __shared__ __align__(16) float sW[64 * 128];   // 32 KB
  __shared__ __align__(16) float sH[64 * 68];    // 17.4 KB (pad 68)
  int tid = threadIdx.x;
  int bm0 = blockIdx.x * 64;
  int tc = tid & 15, tr = tid >> 4;
  int j0 = tc * 8, m0 = tr * 4;
  float acc[4][8];
#pragma unroll
  for (int r = 0; r < 4; ++r)
#pragma unroll
    for (int c = 0; c < 8; ++c) acc[r][c] = 0.f;

  for (int kc = 0; kc < 6; ++kc) {
    int k0 = (kc & 1) * 64;
    __syncthreads();
    const float4* Wg = (const float4*)(W + kc * 64 * 128);
    float4* sW4 = (float4*)sW;
#pragma unroll
    for (int p = 0; p < 8; ++p) sW4[tid + p * 256] = Wg[tid + p * 256];
    float4* sH4 = (float4*)sH;
    if (kc < 2) {
      const float4* Hg = (const float4*)xcur;
#pragma unroll
      for (int p = 0; p < 4; ++p) {
        int f = tid + p * 256;
        int row = f >> 4, c4 = f & 15;
        int v = bm0 + row;
        float4 val = make_float4(0.f, 0.f, 0.f, 0.f);
        if (v < n) val = Hg[(size_t)v * 32 + (k0 >> 2) + c4];
        sH4[row * 17 + c4] = val;
      }
    } else {
      const uint2* Hg = (const uint2*)((kc < 4) ? fwdb : bwdb);
#pragma unroll
      for (int p = 0; p < 4; ++p) {
        int f = tid + p * 256;
        int row = f >> 4, c4 = f & 15;
        int v = bm0 + row;
        float4 val = make_float4(0.f, 0.f, 0.f, 0.f);
        if (v < n) {
          uint2 hb = Hg[(size_t)v * 32 + (k0 >> 2) + c4];
          val = make_float4(bflo(hb.x), bfhi(hb.x), bflo(hb.y), bfhi(hb.y));
        }
        sH4[row * 17 + c4] = val;
      }
    }
    __syncthreads();
#pragma unroll 8
    for (int kk = 0; kk < 64; ++kk) {
      float4 w0 = *(const float4*)&sW[kk * 128 + j0];
      float4 w1 = *(const float4*)&sW[kk * 128 + j0 + 4];
      float hv[4];
      hv[0] = sH[(m0 + 0) * 68 + kk];
      hv[1] = sH[(m0 + 1) * 68 + kk];
      hv[2] = sH[(m0 + 2) * 68 + kk];
      hv[3] = sH[(m0 + 3) * 68 + kk];
      float wv[8] = {w0.x, w0.y, w0.z, w0.w, w1.x, w1.y, w1.z, w1.w};
#pragma unroll
      for (int r = 0; r < 4; ++r)
#pragma unroll
        for (int c = 0; c < 8; ++c) acc[r][c] += hv[r] * wv[c];
    }
  }

  float bj[8];
#pragma unroll
  for (int c = 0; c < 8; ++c) bj[c] = bias[j0 + c];
#pragma unroll
  for (int r = 0; r < 4; ++r) {
    int v = bm0 + m0 + r;
    if (v >= n) continue;
    float o[8];
#pragma unroll
    for (int c = 0; c < 8; ++c) {
      float t = acc[r][c] + bj[c];
      o[c] = relu ? fmaxf(t, 0.f) : t;
    }
    float4* op = (float4*)(out + (size_t)v * 128 + j0);
    op[0] = make_float4(o[0], o[1], o[2], o[3]);
    op[1] = make_float4(o[4], o[5], o[6], o[7]);
  }
}

extern "C" void kernel_launch(void* const* d_in, const int* in_sizes, int n_in,
                              void* d_out, int out_size, void* d_ws, size_t ws_size,
                              hipStream_t stream) {
  const int D = 128;
  const int N = in_sizes[0] / D;
  const int E = in_sizes[7];

  const float* x  = (const float*)d_in[0];
  const float* W0 = (const float*)d_in[1];
  const float* b0 = (const float*)d_in[2];
  const float* W1 = (const float*)d_in[3];
  const float* b1 = (const float*)d_in[4];
  const float* W2 = (const float*)d_in[5];
  const float* b2 = (const float*)d_in[6];
  const int* src  = (const int*)d_in[7];
  const int* dst  = (const int*)d_in[8];
  float* out = (float*)d_out;

  char* p = (char*)d_ws;
  auto alloc = [&](size_t bytes) -> char* {
    char* r = p;
    p += (bytes + 15) & ~(size_t)15;
    return r;
  };
  float* invout = (float*)alloc((size_t)N * 4);
  float* invin  = (float*)alloc((size_t)N * 4);
  int* cntin  = (int*)alloc((size_t)N * 4);
  int* cntout = (int*)alloc((size_t)N * 4);
  int* offf = (int*)alloc((size_t)(N + 1) * 4);
  int* offb = (int*)alloc((size_t)(N + 1) * 4);
  int* rankf = (int*)alloc((size_t)E * 4);
  int* rankb = (int*)alloc((size_t)E * 4);
  int* lstf = (int*)alloc((size_t)E * 4);
  int* lstb = (int*)alloc((size_t)E * 4);
  unsigned* xbo = (unsigned*)alloc((size_t)N * 64 * 4);   // bf16x2 packed
  unsigned* xbi = (unsigned*)alloc((size_t)N * 64 * 4);
  unsigned* fwdb = (unsigned*)alloc((size_t)N * 64 * 4);  // bf16x2 packed
  unsigned* bwdb = (unsigned*)alloc((size_t)N * 64 * 4);
  float* x1 = (float*)alloc((size_t)N * D * 4);

  hipMemsetAsync(cntin, 0, (size_t)2 * N * 4, stream);  // cntin+cntout contiguous

  k_degrees<<<(E + 255) / 256, 256, 0, stream>>>(src, dst, cntin, cntout, rankf,
                                                 rankb, E);
  k_inv<<<(N + 255) / 256, 256, 0, stream>>>(cntin, cntout, invin, invout, N);
  k_scan<<<1, 1024, 0, stream>>>(cntin, offf, N);
  k_scan<<<1, 1024, 0, stream>>>(cntout, offb, N);
  k_fill<<<(E + 255) / 256, 256, 0, stream>>>(src, dst, offf, offb, rankf, rankb,
                                              lstf, lstb, E);

  const float* Ws[3] = {W0, W1, W2};
  const float* bs[3] = {b0, b1, b2};
  int aggBlocks = (N * 64 + 255) / 256;   // one wave per node
  int convBlocks = (N * 32 + 255) / 256;
  for (int l = 0; l < 3; ++l) {
    const float* xc = (l == 0) ? x : ((l == 1) ? x1 : out);
    float* xo = (l == 0) ? x1 : out;
    k_conv<<<convBlocks, 256, 0, stream>>>(xc, invout, invin, xbo, xbi, N);
    // fwd[v] = sum_{s:(s,v)} x[s]*inv_out[s]  (gather xbo via lstf)
    k_agg<<<aggBlocks, 256, 0, stream>>>(xbo, offf, lstf, fwdb, N);
    // bwd[v] = sum_{d:(v,d)} x[d]*inv_in[d]   (gather xbi via lstb)
    k_agg<<<aggBlocks, 256, 0, stream>>>(xbi, offb, lstb, bwdb, N);
    k_gemm<<<(N + 63) / 64, 256, 0, stream>>>(xc, fwdb, bwdb, Ws[l], bs[l], xo, N,
                                              (l < 2) ? 1 : 0);
  }
}

// Round 3
// 716.823 us; speedup vs baseline: 1.5793x; 1.2796x over previous
//
#include <hip/hip_runtime.h>
#include <cstdint>

// ---------------------------------------------------------------------------
// DirGraphSAGE round 2:
//  - CSR build (rank-trick, atomic-free fill) unchanged
//  - bf16 gather aggregation unchanged
//  - GEMM -> bf16 MFMA (16x16x32), split-precision W (W_hi + W_lo, 2 MFMAs
//    into one fp32 acc) so W rounding error is ~2^-17; only xcur bf16
//    rounding adds error. Fragment-ordered LDS => conflict-free ds_read_b128.
// ---------------------------------------------------------------------------

typedef __bf16 bf16x8 __attribute__((ext_vector_type(8)));
typedef float f32x4 __attribute__((ext_vector_type(4)));

__device__ __forceinline__ unsigned short f2bf(float f) {
  unsigned u = __float_as_uint(f);
  u += 0x7FFFu + ((u >> 16) & 1u);   // round-to-nearest-even
  return (unsigned short)(u >> 16);
}
__device__ __forceinline__ float bflo(unsigned u) { return __uint_as_float(u << 16); }
__device__ __forceinline__ float bfhi(unsigned u) { return __uint_as_float(u & 0xFFFF0000u); }

__global__ __launch_bounds__(256) void k_degrees(const int* __restrict__ src,
                                                 const int* __restrict__ dst,
                                                 int* __restrict__ cnt_in,
                                                 int* __restrict__ cnt_out,
                                                 int* __restrict__ rankf,
                                                 int* __restrict__ rankb, int E) {
  int e = blockIdx.x * 256 + threadIdx.x;
  if (e >= E) return;
  int s = src[e], d = dst[e];
  rankf[e] = atomicAdd(&cnt_in[d], 1);   // rank within fwd list (grouped by dst)
  rankb[e] = atomicAdd(&cnt_out[s], 1);  // rank within bwd list (grouped by src)
}

__global__ __launch_bounds__(256) void k_inv(const int* __restrict__ cnt_in,
                                             const int* __restrict__ cnt_out,
                                             float* __restrict__ inv_in,
                                             float* __restrict__ inv_out, int n) {
  int i = blockIdx.x * 256 + threadIdx.x;
  if (i >= n) return;
  inv_out[i] = 1.0f / (float)max(cnt_out[i], 1);
  inv_in[i]  = 1.0f / (float)max(cnt_in[i], 1);
}

// Single-block exclusive scan over n counts -> off[0..n] (off[n] = total).
__global__ __launch_bounds__(1024) void k_scan(const int* __restrict__ cnt,
                                               int* __restrict__ off, int n) {
  __shared__ int part[1024];
  int t = threadIdx.x;
  int CH = (n + 1023) / 1024;
  int base = t * CH;
  int s = 0;
  for (int i = 0; i < CH; ++i) { int idx = base + i; if (idx < n) s += cnt[idx]; }
  part[t] = s;
  __syncthreads();
  for (int o = 1; o < 1024; o <<= 1) {
    int v = (t >= o) ? part[t - o] : 0;
    __syncthreads();
    part[t] += v;
    __syncthreads();
  }
  int run = (t == 0) ? 0 : part[t - 1];
  for (int i = 0; i < CH; ++i) {
    int idx = base + i;
    if (idx < n) { off[idx] = run; run += cnt[idx]; }
  }
  if (t == 1023) off[n] = part[1023];
}

// Atomic-free fill using precomputed ranks.
__global__ __launch_bounds__(256) void k_fill(const int* __restrict__ src,
                                              const int* __restrict__ dst,
                                              const int* __restrict__ offf,
                                              const int* __restrict__ offb,
                                              const int* __restrict__ rankf,
                                              const int* __restrict__ rankb,
                                              int* __restrict__ lstf,
                                              int* __restrict__ lstb, int E) {
  int e = blockIdx.x * 256 + threadIdx.x;
  if (e >= E) return;
  int s = src[e], d = dst[e];
  lstf[offf[d] + rankf[e]] = s;   // fwd: grouped by dst, holds src
  lstb[offb[s] + rankb[e]] = d;   // bwd: grouped by src, holds dst
}

// x (fp32, N x 128) -> xbo = bf16(x*inv_out), xbi = bf16(x*inv_in), xbu = bf16(x)
__global__ __launch_bounds__(256) void k_conv(const float* __restrict__ x,
                                              const float* __restrict__ inv_out,
                                              const float* __restrict__ inv_in,
                                              unsigned* __restrict__ xbo,
                                              unsigned* __restrict__ xbi,
                                              unsigned* __restrict__ xbu, int n) {
  int idx = blockIdx.x * 256 + threadIdx.x;  // over n*32 float4s
  if (idx >= n * 32) return;
  int v = idx >> 5;
  float so = inv_out[v], si = inv_in[v];
  float4 xv = ((const float4*)x)[idx];
  unsigned o0 = (unsigned)f2bf(xv.x * so) | ((unsigned)f2bf(xv.y * so) << 16);
  unsigned o1 = (unsigned)f2bf(xv.z * so) | ((unsigned)f2bf(xv.w * so) << 16);
  ((uint2*)xbo)[idx] = make_uint2(o0, o1);
  unsigned i0 = (unsigned)f2bf(xv.x * si) | ((unsigned)f2bf(xv.y * si) << 16);
  unsigned i1 = (unsigned)f2bf(xv.z * si) | ((unsigned)f2bf(xv.w * si) << 16);
  ((uint2*)xbi)[idx] = make_uint2(i0, i1);
  unsigned u0 = (unsigned)f2bf(xv.x) | ((unsigned)f2bf(xv.y) << 16);
  unsigned u1 = (unsigned)f2bf(xv.z) | ((unsigned)f2bf(xv.w) << 16);
  ((uint2*)xbu)[idx] = make_uint2(u0, u1);
}

// W (fp32 384x128) -> Wt_hi, Wt_lo (bf16, 128x384, transposed, packed x2)
// split precision: W = hi + lo, |lo| <= 2^-9 |W|
__global__ __launch_bounds__(256) void k_wconv(const float* __restrict__ W,
                                               unsigned* __restrict__ Wth,
                                               unsigned* __restrict__ Wtl) {
  int t = blockIdx.x * 256 + threadIdx.x;   // 128*192 threads; t = j*192 + k2
  if (t >= 128 * 192) return;
  int j = t / 192, k2 = t - j * 192;
  int k = k2 * 2;
  float w0 = W[k * 128 + j], w1 = W[(k + 1) * 128 + j];
  unsigned short h0 = f2bf(w0), h1 = f2bf(w1);
  float l0 = w0 - __uint_as_float((unsigned)h0 << 16);
  float l1 = w1 - __uint_as_float((unsigned)h1 << 16);
  Wth[t] = (unsigned)h0 | ((unsigned)h1 << 16);
  Wtl[t] = (unsigned)f2bf(l0) | ((unsigned)f2bf(l1) << 16);
}

// One wave per node: outb[v,:] = bf16( sum_{u in list(v)} xb[u,:] )
__global__ __launch_bounds__(256) void k_agg(const unsigned* __restrict__ xb,
                                             const int* __restrict__ off,
                                             const int* __restrict__ lst,
                                             unsigned* __restrict__ outb, int n) {
  int wave = (blockIdx.x * 256 + threadIdx.x) >> 6;
  int lane = threadIdx.x & 63;
  if (wave >= n) return;
  int beg = off[wave], end = off[wave + 1];
  float ax = 0.f, ay = 0.f;
  int i = beg;
  for (; i + 3 < end; i += 4) {
    int u0 = lst[i], u1 = lst[i + 1], u2 = lst[i + 2], u3 = lst[i + 3];
    unsigned a = xb[(size_t)u0 * 64 + lane];
    unsigned b = xb[(size_t)u1 * 64 + lane];
    unsigned c = xb[(size_t)u2 * 64 + lane];
    unsigned d = xb[(size_t)u3 * 64 + lane];
    ax += bflo(a); ay += bfhi(a);
    ax += bflo(b); ay += bfhi(b);
    ax += bflo(c); ay += bfhi(c);
    ax += bflo(d); ay += bfhi(d);
  }
  for (; i < end; ++i) {
    unsigned a = xb[(size_t)lst[i] * 64 + lane];
    ax += bflo(a); ay += bfhi(a);
  }
  outb[(size_t)wave * 64 + lane] = (unsigned)f2bf(ax) | ((unsigned)f2bf(ay) << 16);
}

// MFMA GEMM: out[v,:] = (relu?)(bias + [xbu|fwdb|bwdb][v,:] @ (W_hi + W_lo))
// BM=128 rows/block, BN=128 (full), BK=32, 256 threads = 4 waves.
// Wave w computes rows [32w, 32w+32): 2 m-tiles x 8 n-tiles of 16x16x32 MFMA,
// 2 MFMAs per tile (W_hi, W_lo) into one fp32 acc.
// LDS fragment-ordered: slot16B[tile*64 + lane] => conflict-free ds_read_b128.
__global__ __launch_bounds__(256) void k_gemm(const unsigned* __restrict__ xbu,
                                              const unsigned* __restrict__ fwdb,
                                              const unsigned* __restrict__ bwdb,
                                              const unsigned* __restrict__ Wth,
                                              const unsigned* __restrict__ Wtl,
                                              const float* __restrict__ bias,
                                              float* __restrict__ out, int n, int relu) {
  __shared__ uint4 sA[512];    // 8 KB: A chunk, frag order [mt][q][m]
  __shared__ uint4 sWh[512];   // 8 KB: W_hi chunk, frag order [nt][q][j&15]
  __shared__ uint4 sWl[512];   // 8 KB
  int tid = threadIdx.x;
  int bm0 = blockIdx.x * 128;
  int w = tid >> 6, lane = tid & 63;

  f32x4 acc[2][8];
#pragma unroll
  for (int mt = 0; mt < 2; ++mt)
#pragma unroll
    for (int nt = 0; nt < 8; ++nt) acc[mt][nt] = (f32x4){0.f, 0.f, 0.f, 0.f};

  const uint4* Wh4 = (const uint4*)Wth;   // row j: 48 uint4 (384 bf16)
  const uint4* Wl4 = (const uint4*)Wtl;

  for (int kc = 0; kc < 12; ++kc) {
    const uint4* src4 = (const uint4*)((kc < 4) ? xbu : ((kc < 8) ? fwdb : bwdb));
    int ko = (kc & 3) * 4;   // uint4 offset within row (16 uint4 = 128 bf16)
    __syncthreads();
#pragma unroll
    for (int p = 0; p < 2; ++p) {
      int f = tid + p * 256;          // 0..511
      int r = f >> 2, q = f & 3;      // r: row/col-of-W, q: k-quad
      int slot = (r >> 4) * 64 + q * 16 + (r & 15);
      int v = bm0 + r;
      uint4 val = make_uint4(0u, 0u, 0u, 0u);
      if (v < n) val = src4[(size_t)v * 16 + ko + q];
      sA[slot] = val;
      sWh[slot] = Wh4[(size_t)r * 48 + kc * 4 + q];
      sWl[slot] = Wl4[(size_t)r * 48 + kc * 4 + q];
    }
    __syncthreads();
    bf16x8 a0 = ((const bf16x8*)sA)[(2 * w) * 64 + lane];
    bf16x8 a1 = ((const bf16x8*)sA)[(2 * w + 1) * 64 + lane];
#pragma unroll
    for (int nt = 0; nt < 8; ++nt) {
      bf16x8 bh = ((const bf16x8*)sWh)[nt * 64 + lane];
      bf16x8 bl = ((const bf16x8*)sWl)[nt * 64 + lane];
      acc[0][nt] = __builtin_amdgcn_mfma_f32_16x16x32_bf16(a0, bh, acc[0][nt], 0, 0, 0);
      acc[0][nt] = __builtin_amdgcn_mfma_f32_16x16x32_bf16(a0, bl, acc[0][nt], 0, 0, 0);
      acc[1][nt] = __builtin_amdgcn_mfma_f32_16x16x32_bf16(a1, bh, acc[1][nt], 0, 0, 0);
      acc[1][nt] = __builtin_amdgcn_mfma_f32_16x16x32_bf16(a1, bl, acc[1][nt], 0, 0, 0);
    }
  }

  // Epilogue. C layout: col = lane&15, row = (lane>>4)*4 + reg  (m89-verified)
  int col = lane & 15;
  float bv[8];
#pragma unroll
  for (int nt = 0; nt < 8; ++nt) bv[nt] = bias[nt * 16 + col];
#pragma unroll
  for (int mt = 0; mt < 2; ++mt) {
    int rowbase = bm0 + w * 32 + mt * 16 + (lane >> 4) * 4;
#pragma unroll
    for (int reg = 0; reg < 4; ++reg) {
      int row = rowbase + reg;
      if (row >= n) continue;
#pragma unroll
      for (int nt = 0; nt < 8; ++nt) {
        float t = acc[mt][nt][reg] + bv[nt];
        out[(size_t)row * 128 + nt * 16 + col] = relu ? fmaxf(t, 0.f) : t;
      }
    }
  }
}

extern "C" void kernel_launch(void* const* d_in, const int* in_sizes, int n_in,
                              void* d_out, int out_size, void* d_ws, size_t ws_size,
                              hipStream_t stream) {
  const int D = 128;
  const int N = in_sizes[0] / D;
  const int E = in_sizes[7];

  const float* x  = (const float*)d_in[0];
  const float* W0 = (const float*)d_in[1];
  const float* b0 = (const float*)d_in[2];
  const float* W1 = (const float*)d_in[3];
  const float* b1 = (const float*)d_in[4];
  const float* W2 = (const float*)d_in[5];
  const float* b2 = (const float*)d_in[6];
  const int* src  = (const int*)d_in[7];
  const int* dst  = (const int*)d_in[8];
  float* out = (float*)d_out;

  char* p = (char*)d_ws;
  auto alloc = [&](size_t bytes) -> char* {
    char* r = p;
    p += (bytes + 15) & ~(size_t)15;
    return r;
  };
  float* invout = (float*)alloc((size_t)N * 4);
  float* invin  = (float*)alloc((size_t)N * 4);
  int* cntin  = (int*)alloc((size_t)N * 4);
  int* cntout = (int*)alloc((size_t)N * 4);
  int* offf = (int*)alloc((size_t)(N + 1) * 4);
  int* offb = (int*)alloc((size_t)(N + 1) * 4);
  int* rankf = (int*)alloc((size_t)E * 4);
  int* rankb = (int*)alloc((size_t)E * 4);
  int* lstf = (int*)alloc((size_t)E * 4);
  int* lstb = (int*)alloc((size_t)E * 4);
  unsigned* xbo = (unsigned*)alloc((size_t)N * 64 * 4);   // bf16x2 packed
  unsigned* xbi = (unsigned*)alloc((size_t)N * 64 * 4);
  unsigned* xbu = (unsigned*)alloc((size_t)N * 64 * 4);
  unsigned* fwdb = (unsigned*)alloc((size_t)N * 64 * 4);
  unsigned* bwdb = (unsigned*)alloc((size_t)N * 64 * 4);
  float* x1 = (float*)alloc((size_t)N * D * 4);
  unsigned* Wth[3], *Wtl[3];
  for (int l = 0; l < 3; ++l) {
    Wth[l] = (unsigned*)alloc((size_t)128 * 192 * 4);
    Wtl[l] = (unsigned*)alloc((size_t)128 * 192 * 4);
  }

  hipMemsetAsync(cntin, 0, (size_t)2 * N * 4, stream);  // cntin+cntout contiguous

  k_degrees<<<(E + 255) / 256, 256, 0, stream>>>(src, dst, cntin, cntout, rankf,
                                                 rankb, E);
  k_inv<<<(N + 255) / 256, 256, 0, stream>>>(cntin, cntout, invin, invout, N);
  k_scan<<<1, 1024, 0, stream>>>(cntin, offf, N);
  k_scan<<<1, 1024, 0, stream>>>(cntout, offb, N);
  k_fill<<<(E + 255) / 256, 256, 0, stream>>>(src, dst, offf, offb, rankf, rankb,
                                              lstf, lstb, E);
  const float* Ws[3] = {W0, W1, W2};
  const float* bs[3] = {b0, b1, b2};
  for (int l = 0; l < 3; ++l)
    k_wconv<<<(128 * 192 + 255) / 256, 256, 0, stream>>>(Ws[l], Wth[l], Wtl[l]);

  int aggBlocks = (N * 64 + 255) / 256;   // one wave per node
  int convBlocks = (N * 32 + 255) / 256;
  int gemmBlocks = (N + 127) / 128;
  for (int l = 0; l < 3; ++l) {
    const float* xc = (l == 0) ? x : ((l == 1) ? x1 : out);
    float* xo = (l == 0) ? x1 : out;
    k_conv<<<convBlocks, 256, 0, stream>>>(xc, invout, invin, xbo, xbi, xbu, N);
    k_agg<<<aggBlocks, 256, 0, stream>>>(xbo, offf, lstf, fwdb, N);
    k_agg<<<aggBlocks, 256, 0, stream>>>(xbi, offb, lstb, bwdb, N);
    k_gemm<<<gemmBlocks, 256, 0, stream>>>(xbu, fwdb, bwdb, Wth[l], Wtl[l], bs[l],
                                           xo, N, (l < 2) ? 1 : 0);
  }
}

// Round 4
// 542.495 us; speedup vs baseline: 2.0868x; 1.3213x over previous
//
#include <hip/hip_runtime.h>
#include <cstdint>

// ---------------------------------------------------------------------------
// DirGraphSAGE round 3:
//  - replace single-block k_scan (95us x2, 0.16% occupancy!) with a 3-phase
//    multi-block scan; both directions fused per launch via gridDim.y=2
//  - everything else unchanged (rank-trick CSR, bf16 gather agg, split-W MFMA GEMM)
// ---------------------------------------------------------------------------

typedef __bf16 bf16x8 __attribute__((ext_vector_type(8)));
typedef float f32x4 __attribute__((ext_vector_type(4)));

__device__ __forceinline__ unsigned short f2bf(float f) {
  unsigned u = __float_as_uint(f);
  u += 0x7FFFu + ((u >> 16) & 1u);   // round-to-nearest-even
  return (unsigned short)(u >> 16);
}
__device__ __forceinline__ float bflo(unsigned u) { return __uint_as_float(u << 16); }
__device__ __forceinline__ float bfhi(unsigned u) { return __uint_as_float(u & 0xFFFF0000u); }

__global__ __launch_bounds__(256) void k_degrees(const int* __restrict__ src,
                                                 const int* __restrict__ dst,
                                                 int* __restrict__ cnt_in,
                                                 int* __restrict__ cnt_out,
                                                 int* __restrict__ rankf,
                                                 int* __restrict__ rankb, int E) {
  int e = blockIdx.x * 256 + threadIdx.x;
  if (e >= E) return;
  int s = src[e], d = dst[e];
  rankf[e] = atomicAdd(&cnt_in[d], 1);   // rank within fwd list (grouped by dst)
  rankb[e] = atomicAdd(&cnt_out[s], 1);  // rank within bwd list (grouped by src)
}

__global__ __launch_bounds__(256) void k_inv(const int* __restrict__ cnt_in,
                                             const int* __restrict__ cnt_out,
                                             float* __restrict__ inv_in,
                                             float* __restrict__ inv_out, int n) {
  int i = blockIdx.x * 256 + threadIdx.x;
  if (i >= n) return;
  inv_out[i] = 1.0f / (float)max(cnt_out[i], 1);
  inv_in[i]  = 1.0f / (float)max(cnt_in[i], 1);
}

// --- 3-phase multi-block exclusive scan (CHUNK=2048/block, y-dim = which array)
__global__ __launch_bounds__(256) void k_scan_part(const int* __restrict__ cntA,
                                                   const int* __restrict__ cntB,
                                                   int* __restrict__ partA,
                                                   int* __restrict__ partB, int n) {
  const int* cnt = blockIdx.y ? cntB : cntA;
  int* part = blockIdx.y ? partB : partA;
  __shared__ int red[256];
  int t = threadIdx.x;
  int base = blockIdx.x * 2048 + t * 8;
  int s = 0;
#pragma unroll
  for (int i = 0; i < 8; ++i) {
    int idx = base + i;
    if (idx < n) s += cnt[idx];
  }
  red[t] = s;
  __syncthreads();
  for (int o = 128; o > 0; o >>= 1) {
    if (t < o) red[t] += red[t + o];
    __syncthreads();
  }
  if (t == 0) part[blockIdx.x] = red[0];
}

__global__ __launch_bounds__(64) void k_scan_tops(int* __restrict__ partA,
                                                  int* __restrict__ partB, int nb) {
  int* part = blockIdx.y ? partB : partA;
  if (threadIdx.x == 0) {
    int run = 0;
    for (int i = 0; i < nb; ++i) { int v = part[i]; part[i] = run; run += v; }
  }
}

__global__ __launch_bounds__(256) void k_scan_out(const int* __restrict__ cntA,
                                                  const int* __restrict__ cntB,
                                                  const int* __restrict__ partA,
                                                  const int* __restrict__ partB,
                                                  int* __restrict__ offA,
                                                  int* __restrict__ offB, int n) {
  const int* cnt = blockIdx.y ? cntB : cntA;
  const int* part = blockIdx.y ? partB : partA;
  int* off = blockIdx.y ? offB : offA;
  __shared__ int ts[256];
  int t = threadIdx.x;
  int base = blockIdx.x * 2048 + t * 8;
  int v[8];
  int s = 0;
#pragma unroll
  for (int i = 0; i < 8; ++i) {
    int idx = base + i;
    int c = (idx < n) ? cnt[idx] : 0;
    v[i] = s;          // exclusive prefix within thread
    s += c;
  }
  ts[t] = s;
  __syncthreads();
  for (int o = 1; o < 256; o <<= 1) {
    int val = (t >= o) ? ts[t - o] : 0;
    __syncthreads();
    ts[t] += val;
    __syncthreads();
  }
  int blockbase = part[blockIdx.x] + (t ? ts[t - 1] : 0);
#pragma unroll
  for (int i = 0; i < 8; ++i) {
    int idx = base + i;
    if (idx <= n) off[idx] = blockbase + v[i];   // idx==n writes the total
  }
}

// Atomic-free fill using precomputed ranks.
__global__ __launch_bounds__(256) void k_fill(const int* __restrict__ src,
                                              const int* __restrict__ dst,
                                              const int* __restrict__ offf,
                                              const int* __restrict__ offb,
                                              const int* __restrict__ rankf,
                                              const int* __restrict__ rankb,
                                              int* __restrict__ lstf,
                                              int* __restrict__ lstb, int E) {
  int e = blockIdx.x * 256 + threadIdx.x;
  if (e >= E) return;
  int s = src[e], d = dst[e];
  lstf[offf[d] + rankf[e]] = s;   // fwd: grouped by dst, holds src
  lstb[offb[s] + rankb[e]] = d;   // bwd: grouped by src, holds dst
}

// x (fp32, N x 128) -> xbo = bf16(x*inv_out), xbi = bf16(x*inv_in), xbu = bf16(x)
__global__ __launch_bounds__(256) void k_conv(const float* __restrict__ x,
                                              const float* __restrict__ inv_out,
                                              const float* __restrict__ inv_in,
                                              unsigned* __restrict__ xbo,
                                              unsigned* __restrict__ xbi,
                                              unsigned* __restrict__ xbu, int n) {
  int idx = blockIdx.x * 256 + threadIdx.x;  // over n*32 float4s
  if (idx >= n * 32) return;
  int v = idx >> 5;
  float so = inv_out[v], si = inv_in[v];
  float4 xv = ((const float4*)x)[idx];
  unsigned o0 = (unsigned)f2bf(xv.x * so) | ((unsigned)f2bf(xv.y * so) << 16);
  unsigned o1 = (unsigned)f2bf(xv.z * so) | ((unsigned)f2bf(xv.w * so) << 16);
  ((uint2*)xbo)[idx] = make_uint2(o0, o1);
  unsigned i0 = (unsigned)f2bf(xv.x * si) | ((unsigned)f2bf(xv.y * si) << 16);
  unsigned i1 = (unsigned)f2bf(xv.z * si) | ((unsigned)f2bf(xv.w * si) << 16);
  ((uint2*)xbi)[idx] = make_uint2(i0, i1);
  unsigned u0 = (unsigned)f2bf(xv.x) | ((unsigned)f2bf(xv.y) << 16);
  unsigned u1 = (unsigned)f2bf(xv.z) | ((unsigned)f2bf(xv.w) << 16);
  ((uint2*)xbu)[idx] = make_uint2(u0, u1);
}

// W (fp32 384x128) -> Wt_hi, Wt_lo (bf16, 128x384, transposed, packed x2)
__global__ __launch_bounds__(256) void k_wconv(const float* __restrict__ W,
                                               unsigned* __restrict__ Wth,
                                               unsigned* __restrict__ Wtl) {
  int t = blockIdx.x * 256 + threadIdx.x;   // 128*192 threads; t = j*192 + k2
  if (t >= 128 * 192) return;
  int j = t / 192, k2 = t - j * 192;
  int k = k2 * 2;
  float w0 = W[k * 128 + j], w1 = W[(k + 1) * 128 + j];
  unsigned short h0 = f2bf(w0), h1 = f2bf(w1);
  float l0 = w0 - __uint_as_float((unsigned)h0 << 16);
  float l1 = w1 - __uint_as_float((unsigned)h1 << 16);
  Wth[t] = (unsigned)h0 | ((unsigned)h1 << 16);
  Wtl[t] = (unsigned)f2bf(l0) | ((unsigned)f2bf(l1) << 16);
}

// One wave per node: outb[v,:] = bf16( sum_{u in list(v)} xb[u,:] )
__global__ __launch_bounds__(256) void k_agg(const unsigned* __restrict__ xb,
                                             const int* __restrict__ off,
                                             const int* __restrict__ lst,
                                             unsigned* __restrict__ outb, int n) {
  int wave = (blockIdx.x * 256 + threadIdx.x) >> 6;
  int lane = threadIdx.x & 63;
  if (wave >= n) return;
  int beg = off[wave], end = off[wave + 1];
  float ax = 0.f, ay = 0.f;
  int i = beg;
  for (; i + 3 < end; i += 4) {
    int u0 = lst[i], u1 = lst[i + 1], u2 = lst[i + 2], u3 = lst[i + 3];
    unsigned a = xb[(size_t)u0 * 64 + lane];
    unsigned b = xb[(size_t)u1 * 64 + lane];
    unsigned c = xb[(size_t)u2 * 64 + lane];
    unsigned d = xb[(size_t)u3 * 64 + lane];
    ax += bflo(a); ay += bfhi(a);
    ax += bflo(b); ay += bfhi(b);
    ax += bflo(c); ay += bfhi(c);
    ax += bflo(d); ay += bfhi(d);
  }
  for (; i < end; ++i) {
    unsigned a = xb[(size_t)lst[i] * 64 + lane];
    ax += bflo(a); ay += bfhi(a);
  }
  outb[(size_t)wave * 64 + lane] = (unsigned)f2bf(ax) | ((unsigned)f2bf(ay) << 16);
}

// MFMA GEMM: out[v,:] = (relu?)(bias + [xbu|fwdb|bwdb][v,:] @ (W_hi + W_lo))
__global__ __launch_bounds__(256) void k_gemm(const unsigned* __restrict__ xbu,
                                              const unsigned* __restrict__ fwdb,
                                              const unsigned* __restrict__ bwdb,
                                              const unsigned* __restrict__ Wth,
                                              const unsigned* __restrict__ Wtl,
                                              const float* __restrict__ bias,
                                              float* __restrict__ out, int n, int relu) {
  __shared__ uint4 sA[512];    // 8 KB: A chunk, frag order [mt][q][m]
  __shared__ uint4 sWh[512];   // 8 KB: W_hi chunk, frag order [nt][q][j&15]
  __shared__ uint4 sWl[512];   // 8 KB
  int tid = threadIdx.x;
  int bm0 = blockIdx.x * 128;
  int w = tid >> 6, lane = tid & 63;

  f32x4 acc[2][8];
#pragma unroll
  for (int mt = 0; mt < 2; ++mt)
#pragma unroll
    for (int nt = 0; nt < 8; ++nt) acc[mt][nt] = (f32x4){0.f, 0.f, 0.f, 0.f};

  const uint4* Wh4 = (const uint4*)Wth;   // row j: 48 uint4 (384 bf16)
  const uint4* Wl4 = (const uint4*)Wtl;

  for (int kc = 0; kc < 12; ++kc) {
    const uint4* src4 = (const uint4*)((kc < 4) ? xbu : ((kc < 8) ? fwdb : bwdb));
    int ko = (kc & 3) * 4;   // uint4 offset within row (16 uint4 = 128 bf16)
    __syncthreads();
#pragma unroll
    for (int p = 0; p < 2; ++p) {
      int f = tid + p * 256;          // 0..511
      int r = f >> 2, q = f & 3;      // r: row/col-of-W, q: k-quad
      int slot = (r >> 4) * 64 + q * 16 + (r & 15);
      int v = bm0 + r;
      uint4 val = make_uint4(0u, 0u, 0u, 0u);
      if (v < n) val = src4[(size_t)v * 16 + ko + q];
      sA[slot] = val;
      sWh[slot] = Wh4[(size_t)r * 48 + kc * 4 + q];
      sWl[slot] = Wl4[(size_t)r * 48 + kc * 4 + q];
    }
    __syncthreads();
    bf16x8 a0 = ((const bf16x8*)sA)[(2 * w) * 64 + lane];
    bf16x8 a1 = ((const bf16x8*)sA)[(2 * w + 1) * 64 + lane];
#pragma unroll
    for (int nt = 0; nt < 8; ++nt) {
      bf16x8 bh = ((const bf16x8*)sWh)[nt * 64 + lane];
      bf16x8 bl = ((const bf16x8*)sWl)[nt * 64 + lane];
      acc[0][nt] = __builtin_amdgcn_mfma_f32_16x16x32_bf16(a0, bh, acc[0][nt], 0, 0, 0);
      acc[0][nt] = __builtin_amdgcn_mfma_f32_16x16x32_bf16(a0, bl, acc[0][nt], 0, 0, 0);
      acc[1][nt] = __builtin_amdgcn_mfma_f32_16x16x32_bf16(a1, bh, acc[1][nt], 0, 0, 0);
      acc[1][nt] = __builtin_amdgcn_mfma_f32_16x16x32_bf16(a1, bl, acc[1][nt], 0, 0, 0);
    }
  }

  // Epilogue. C layout: col = lane&15, row = (lane>>4)*4 + reg  (m89-verified)
  int col = lane & 15;
  float bv[8];
#pragma unroll
  for (int nt = 0; nt < 8; ++nt) bv[nt] = bias[nt * 16 + col];
#pragma unroll
  for (int mt = 0; mt < 2; ++mt) {
    int rowbase = bm0 + w * 32 + mt * 16 + (lane >> 4) * 4;
#pragma unroll
    for (int reg = 0; reg < 4; ++reg) {
      int row = rowbase + reg;
      if (row >= n) continue;
#pragma unroll
      for (int nt = 0; nt < 8; ++nt) {
        float t = acc[mt][nt][reg] + bv[nt];
        out[(size_t)row * 128 + nt * 16 + col] = relu ? fmaxf(t, 0.f) : t;
      }
    }
  }
}

extern "C" void kernel_launch(void* const* d_in, const int* in_sizes, int n_in,
                              void* d_out, int out_size, void* d_ws, size_t ws_size,
                              hipStream_t stream) {
  const int D = 128;
  const int N = in_sizes[0] / D;
  const int E = in_sizes[7];

  const float* x  = (const float*)d_in[0];
  const float* W0 = (const float*)d_in[1];
  const float* b0 = (const float*)d_in[2];
  const float* W1 = (const float*)d_in[3];
  const float* b1 = (const float*)d_in[4];
  const float* W2 = (const float*)d_in[5];
  const float* b2 = (const float*)d_in[6];
  const int* src  = (const int*)d_in[7];
  const int* dst  = (const int*)d_in[8];
  float* out = (float*)d_out;

  char* p = (char*)d_ws;
  auto alloc = [&](size_t bytes) -> char* {
    char* r = p;
    p += (bytes + 15) & ~(size_t)15;
    return r;
  };
  float* invout = (float*)alloc((size_t)N * 4);
  float* invin  = (float*)alloc((size_t)N * 4);
  int* cntin  = (int*)alloc((size_t)N * 4);
  int* cntout = (int*)alloc((size_t)N * 4);
  int* offf = (int*)alloc((size_t)(N + 1) * 4);
  int* offb = (int*)alloc((size_t)(N + 1) * 4);
  int* rankf = (int*)alloc((size_t)E * 4);
  int* rankb = (int*)alloc((size_t)E * 4);
  int* lstf = (int*)alloc((size_t)E * 4);
  int* lstb = (int*)alloc((size_t)E * 4);
  unsigned* xbo = (unsigned*)alloc((size_t)N * 64 * 4);   // bf16x2 packed
  unsigned* xbi = (unsigned*)alloc((size_t)N * 64 * 4);
  unsigned* xbu = (unsigned*)alloc((size_t)N * 64 * 4);
  unsigned* fwdb = (unsigned*)alloc((size_t)N * 64 * 4);
  unsigned* bwdb = (unsigned*)alloc((size_t)N * 64 * 4);
  float* x1 = (float*)alloc((size_t)N * D * 4);
  unsigned* Wth[3], *Wtl[3];
  for (int l = 0; l < 3; ++l) {
    Wth[l] = (unsigned*)alloc((size_t)128 * 192 * 4);
    Wtl[l] = (unsigned*)alloc((size_t)128 * 192 * 4);
  }
  int nbScan = (N + 1 + 2047) / 2048;       // blocks covering n+1 virtual elems
  int* partA = (int*)alloc((size_t)(nbScan + 1) * 4);
  int* partB = (int*)alloc((size_t)(nbScan + 1) * 4);

  hipMemsetAsync(cntin, 0, (size_t)2 * N * 4, stream);  // cntin+cntout contiguous

  k_degrees<<<(E + 255) / 256, 256, 0, stream>>>(src, dst, cntin, cntout, rankf,
                                                 rankb, E);
  k_inv<<<(N + 255) / 256, 256, 0, stream>>>(cntin, cntout, invin, invout, N);
  k_scan_part<<<dim3(nbScan, 2), 256, 0, stream>>>(cntin, cntout, partA, partB, N);
  k_scan_tops<<<dim3(1, 2), 64, 0, stream>>>(partA, partB, nbScan);
  k_scan_out<<<dim3(nbScan, 2), 256, 0, stream>>>(cntin, cntout, partA, partB,
                                                  offf, offb, N);
  k_fill<<<(E + 255) / 256, 256, 0, stream>>>(src, dst, offf, offb, rankf, rankb,
                                              lstf, lstb, E);
  const float* Ws[3] = {W0, W1, W2};
  const float* bs[3] = {b0, b1, b2};
  for (int l = 0; l < 3; ++l)
    k_wconv<<<(128 * 192 + 255) / 256, 256, 0, stream>>>(Ws[l], Wth[l], Wtl[l]);

  int aggBlocks = (N * 64 + 255) / 256;   // one wave per node
  int convBlocks = (N * 32 + 255) / 256;
  int gemmBlocks = (N + 127) / 128;
  for (int l = 0; l < 3; ++l) {
    const float* xc = (l == 0) ? x : ((l == 1) ? x1 : out);
    float* xo = (l == 0) ? x1 : out;
    k_conv<<<convBlocks, 256, 0, stream>>>(xc, invout, invin, xbo, xbi, xbu, N);
    k_agg<<<aggBlocks, 256, 0, stream>>>(xbo, offf, lstf, fwdb, N);
    k_agg<<<aggBlocks, 256, 0, stream>>>(xbi, offb, lstb, bwdb, N);
    k_gemm<<<gemmBlocks, 256, 0, stream>>>(xbu, fwdb, bwdb, Wth[l], Wtl[l], bs[l],
                                           xo, N, (l < 2) ? 1 : 0);
  }
}

// Round 5
// 509.893 us; speedup vs baseline: 2.2202x; 1.0639x over previous
//
#include <hip/hip_runtime.h>
#include <cstdint>

// ---------------------------------------------------------------------------
// DirGraphSAGE round 4:
//  - k_agg redesign: uint4 lanes (16 lanes/edge -> 4 edges per wave-instr,
//    1KB/gather-instr), per-edge fp32 inv scale on UNSCALED bf16 x rows
//    (one shared 12.8MB gather footprint for both directions), fwd+bwd fused
//    in one launch via gridDim.y=2, shfl_xor cross-slot reduction.
//  - k_conv now emits only xbu (saves 2/3 of its write traffic)
//  - CSR build, scan, split-W MFMA GEMM unchanged
// ---------------------------------------------------------------------------

typedef __bf16 bf16x8 __attribute__((ext_vector_type(8)));
typedef float f32x4 __attribute__((ext_vector_type(4)));

__device__ __forceinline__ unsigned short f2bf(float f) {
  unsigned u = __float_as_uint(f);
  u += 0x7FFFu + ((u >> 16) & 1u);   // round-to-nearest-even
  return (unsigned short)(u >> 16);
}
__device__ __forceinline__ float bflo(unsigned u) { return __uint_as_float(u << 16); }
__device__ __forceinline__ float bfhi(unsigned u) { return __uint_as_float(u & 0xFFFF0000u); }

__global__ __launch_bounds__(256) void k_degrees(const int* __restrict__ src,
                                                 const int* __restrict__ dst,
                                                 int* __restrict__ cnt_in,
                                                 int* __restrict__ cnt_out,
                                                 int* __restrict__ rankf,
                                                 int* __restrict__ rankb, int E) {
  int e = blockIdx.x * 256 + threadIdx.x;
  if (e >= E) return;
  int s = src[e], d = dst[e];
  rankf[e] = atomicAdd(&cnt_in[d], 1);   // rank within fwd list (grouped by dst)
  rankb[e] = atomicAdd(&cnt_out[s], 1);  // rank within bwd list (grouped by src)
}

__global__ __launch_bounds__(256) void k_inv(const int* __restrict__ cnt_in,
                                             const int* __restrict__ cnt_out,
                                             float* __restrict__ inv_in,
                                             float* __restrict__ inv_out, int n) {
  int i = blockIdx.x * 256 + threadIdx.x;
  if (i >= n) return;
  inv_out[i] = 1.0f / (float)max(cnt_out[i], 1);
  inv_in[i]  = 1.0f / (float)max(cnt_in[i], 1);
}

// --- 3-phase multi-block exclusive scan (CHUNK=2048/block, y-dim = which array)
__global__ __launch_bounds__(256) void k_scan_part(const int* __restrict__ cntA,
                                                   const int* __restrict__ cntB,
                                                   int* __restrict__ partA,
                                                   int* __restrict__ partB, int n) {
  const int* cnt = blockIdx.y ? cntB : cntA;
  int* part = blockIdx.y ? partB : partA;
  __shared__ int red[256];
  int t = threadIdx.x;
  int base = blockIdx.x * 2048 + t * 8;
  int s = 0;
#pragma unroll
  for (int i = 0; i < 8; ++i) {
    int idx = base + i;
    if (idx < n) s += cnt[idx];
  }
  red[t] = s;
  __syncthreads();
  for (int o = 128; o > 0; o >>= 1) {
    if (t < o) red[t] += red[t + o];
    __syncthreads();
  }
  if (t == 0) part[blockIdx.x] = red[0];
}

__global__ __launch_bounds__(64) void k_scan_tops(int* __restrict__ partA,
                                                  int* __restrict__ partB, int nb) {
  int* part = blockIdx.y ? partB : partA;
  if (threadIdx.x == 0) {
    int run = 0;
    for (int i = 0; i < nb; ++i) { int v = part[i]; part[i] = run; run += v; }
  }
}

__global__ __launch_bounds__(256) void k_scan_out(const int* __restrict__ cntA,
                                                  const int* __restrict__ cntB,
                                                  const int* __restrict__ partA,
                                                  const int* __restrict__ partB,
                                                  int* __restrict__ offA,
                                                  int* __restrict__ offB, int n) {
  const int* cnt = blockIdx.y ? cntB : cntA;
  const int* part = blockIdx.y ? partB : partA;
  int* off = blockIdx.y ? offB : offA;
  __shared__ int ts[256];
  int t = threadIdx.x;
  int base = blockIdx.x * 2048 + t * 8;
  int v[8];
  int s = 0;
#pragma unroll
  for (int i = 0; i < 8; ++i) {
    int idx = base + i;
    int c = (idx < n) ? cnt[idx] : 0;
    v[i] = s;          // exclusive prefix within thread
    s += c;
  }
  ts[t] = s;
  __syncthreads();
  for (int o = 1; o < 256; o <<= 1) {
    int val = (t >= o) ? ts[t - o] : 0;
    __syncthreads();
    ts[t] += val;
    __syncthreads();
  }
  int blockbase = part[blockIdx.x] + (t ? ts[t - 1] : 0);
#pragma unroll
  for (int i = 0; i < 8; ++i) {
    int idx = base + i;
    if (idx <= n) off[idx] = blockbase + v[i];   // idx==n writes the total
  }
}

// Atomic-free fill using precomputed ranks.
__global__ __launch_bounds__(256) void k_fill(const int* __restrict__ src,
                                              const int* __restrict__ dst,
                                              const int* __restrict__ offf,
                                              const int* __restrict__ offb,
                                              const int* __restrict__ rankf,
                                              const int* __restrict__ rankb,
                                              int* __restrict__ lstf,
                                              int* __restrict__ lstb, int E) {
  int e = blockIdx.x * 256 + threadIdx.x;
  if (e >= E) return;
  int s = src[e], d = dst[e];
  lstf[offf[d] + rankf[e]] = s;   // fwd: grouped by dst, holds src
  lstb[offb[s] + rankb[e]] = d;   // bwd: grouped by src, holds dst
}

// x (fp32, N x 128) -> xbu = bf16(x), packed bf16x2
__global__ __launch_bounds__(256) void k_conv(const float* __restrict__ x,
                                              unsigned* __restrict__ xbu, int n) {
  int idx = blockIdx.x * 256 + threadIdx.x;  // over n*32 float4s
  if (idx >= n * 32) return;
  float4 xv = ((const float4*)x)[idx];
  unsigned u0 = (unsigned)f2bf(xv.x) | ((unsigned)f2bf(xv.y) << 16);
  unsigned u1 = (unsigned)f2bf(xv.z) | ((unsigned)f2bf(xv.w) << 16);
  ((uint2*)xbu)[idx] = make_uint2(u0, u1);
}

// W (fp32 384x128) -> Wt_hi, Wt_lo (bf16, 128x384, transposed, packed x2)
__global__ __launch_bounds__(256) void k_wconv(const float* __restrict__ W,
                                               unsigned* __restrict__ Wth,
                                               unsigned* __restrict__ Wtl) {
  int t = blockIdx.x * 256 + threadIdx.x;   // 128*192 threads; t = j*192 + k2
  if (t >= 128 * 192) return;
  int j = t / 192, k2 = t - j * 192;
  int k = k2 * 2;
  float w0 = W[k * 128 + j], w1 = W[(k + 1) * 128 + j];
  unsigned short h0 = f2bf(w0), h1 = f2bf(w1);
  float l0 = w0 - __uint_as_float((unsigned)h0 << 16);
  float l1 = w1 - __uint_as_float((unsigned)h1 << 16);
  Wth[t] = (unsigned)h0 | ((unsigned)h1 << 16);
  Wtl[t] = (unsigned)f2bf(l0) | ((unsigned)f2bf(l1) << 16);
}

// Fused fwd+bwd aggregation. One wave per node per direction (gridDim.y: 0=fwd,
// 1=bwd). 16 lanes per edge slot (uint4 = 8 bf16 cols), 4 slots/wave, 8 edges
// per loop iter. acc in fp32 with per-edge inv[u] scale; shfl_xor combine.
__global__ __launch_bounds__(256) void k_agg2(const uint4* __restrict__ xb,
                                              const int* __restrict__ offA,
                                              const int* __restrict__ lstA,
                                              const float* __restrict__ invA,
                                              const int* __restrict__ offB,
                                              const int* __restrict__ lstB,
                                              const float* __restrict__ invB,
                                              uint4* __restrict__ outA,
                                              uint4* __restrict__ outB, int n) {
  int wave = (blockIdx.x * 256 + threadIdx.x) >> 6;
  if (wave >= n) return;
  const int* off = blockIdx.y ? offB : offA;
  const int* lst = blockIdx.y ? lstB : lstA;
  const float* inv = blockIdx.y ? invB : invA;
  uint4* out = blockIdx.y ? outB : outA;

  int lane = threadIdx.x & 63;
  int g = lane >> 4;    // edge slot 0..3
  int c = lane & 15;    // uint4 column within row (8 bf16 cols)
  int beg = off[wave], end = off[wave + 1];

  float acc[8];
#pragma unroll
  for (int k = 0; k < 8; ++k) acc[k] = 0.f;

  for (int i = beg; i < end; i += 8) {
    int e0 = i + g, e1 = i + 4 + g;
    if (e0 < end) {
      int u = lst[e0];
      float w = inv[u];
      uint4 r = xb[(size_t)u * 16 + c];
      acc[0] = fmaf(bflo(r.x), w, acc[0]); acc[1] = fmaf(bfhi(r.x), w, acc[1]);
      acc[2] = fmaf(bflo(r.y), w, acc[2]); acc[3] = fmaf(bfhi(r.y), w, acc[3]);
      acc[4] = fmaf(bflo(r.z), w, acc[4]); acc[5] = fmaf(bfhi(r.z), w, acc[5]);
      acc[6] = fmaf(bflo(r.w), w, acc[6]); acc[7] = fmaf(bfhi(r.w), w, acc[7]);
    }
    if (e1 < end) {
      int u = lst[e1];
      float w = inv[u];
      uint4 r = xb[(size_t)u * 16 + c];
      acc[0] = fmaf(bflo(r.x), w, acc[0]); acc[1] = fmaf(bfhi(r.x), w, acc[1]);
      acc[2] = fmaf(bflo(r.y), w, acc[2]); acc[3] = fmaf(bfhi(r.y), w, acc[3]);
      acc[4] = fmaf(bflo(r.z), w, acc[4]); acc[5] = fmaf(bfhi(r.z), w, acc[5]);
      acc[6] = fmaf(bflo(r.w), w, acc[6]); acc[7] = fmaf(bfhi(r.w), w, acc[7]);
    }
  }
#pragma unroll
  for (int k = 0; k < 8; ++k) acc[k] += __shfl_xor(acc[k], 32, 64);
#pragma unroll
  for (int k = 0; k < 8; ++k) acc[k] += __shfl_xor(acc[k], 16, 64);
  if (g == 0) {
    uint4 o;
    o.x = (unsigned)f2bf(acc[0]) | ((unsigned)f2bf(acc[1]) << 16);
    o.y = (unsigned)f2bf(acc[2]) | ((unsigned)f2bf(acc[3]) << 16);
    o.z = (unsigned)f2bf(acc[4]) | ((unsigned)f2bf(acc[5]) << 16);
    o.w = (unsigned)f2bf(acc[6]) | ((unsigned)f2bf(acc[7]) << 16);
    out[(size_t)wave * 16 + c] = o;
  }
}

// MFMA GEMM: out[v,:] = (relu?)(bias + [xbu|fwdb|bwdb][v,:] @ (W_hi + W_lo))
__global__ __launch_bounds__(256) void k_gemm(const unsigned* __restrict__ xbu,
                                              const unsigned* __restrict__ fwdb,
                                              const unsigned* __restrict__ bwdb,
                                              const unsigned* __restrict__ Wth,
                                              const unsigned* __restrict__ Wtl,
                                              const float* __restrict__ bias,
                                              float* __restrict__ out, int n, int relu) {
  __shared__ uint4 sA[512];    // 8 KB: A chunk, frag order [mt][q][m]
  __shared__ uint4 sWh[512];   // 8 KB: W_hi chunk, frag order [nt][q][j&15]
  __shared__ uint4 sWl[512];   // 8 KB
  int tid = threadIdx.x;
  int bm0 = blockIdx.x * 128;
  int w = tid >> 6, lane = tid & 63;

  f32x4 acc[2][8];
#pragma unroll
  for (int mt = 0; mt < 2; ++mt)
#pragma unroll
    for (int nt = 0; nt < 8; ++nt) acc[mt][nt] = (f32x4){0.f, 0.f, 0.f, 0.f};

  const uint4* Wh4 = (const uint4*)Wth;   // row j: 48 uint4 (384 bf16)
  const uint4* Wl4 = (const uint4*)Wtl;

  for (int kc = 0; kc < 12; ++kc) {
    const uint4* src4 = (const uint4*)((kc < 4) ? xbu : ((kc < 8) ? fwdb : bwdb));
    int ko = (kc & 3) * 4;   // uint4 offset within row (16 uint4 = 128 bf16)
    __syncthreads();
#pragma unroll
    for (int p = 0; p < 2; ++p) {
      int f = tid + p * 256;          // 0..511
      int r = f >> 2, q = f & 3;      // r: row/col-of-W, q: k-quad
      int slot = (r >> 4) * 64 + q * 16 + (r & 15);
      int v = bm0 + r;
      uint4 val = make_uint4(0u, 0u, 0u, 0u);
      if (v < n) val = src4[(size_t)v * 16 + ko + q];
      sA[slot] = val;
      sWh[slot] = Wh4[(size_t)r * 48 + kc * 4 + q];
      sWl[slot] = Wl4[(size_t)r * 48 + kc * 4 + q];
    }
    __syncthreads();
    bf16x8 a0 = ((const bf16x8*)sA)[(2 * w) * 64 + lane];
    bf16x8 a1 = ((const bf16x8*)sA)[(2 * w + 1) * 64 + lane];
#pragma unroll
    for (int nt = 0; nt < 8; ++nt) {
      bf16x8 bh = ((const bf16x8*)sWh)[nt * 64 + lane];
      bf16x8 bl = ((const bf16x8*)sWl)[nt * 64 + lane];
      acc[0][nt] = __builtin_amdgcn_mfma_f32_16x16x32_bf16(a0, bh, acc[0][nt], 0, 0, 0);
      acc[0][nt] = __builtin_amdgcn_mfma_f32_16x16x32_bf16(a0, bl, acc[0][nt], 0, 0, 0);
      acc[1][nt] = __builtin_amdgcn_mfma_f32_16x16x32_bf16(a1, bh, acc[1][nt], 0, 0, 0);
      acc[1][nt] = __builtin_amdgcn_mfma_f32_16x16x32_bf16(a1, bl, acc[1][nt], 0, 0, 0);
    }
  }

  // Epilogue. C layout: col = lane&15, row = (lane>>4)*4 + reg  (m89-verified)
  int col = lane & 15;
  float bv[8];
#pragma unroll
  for (int nt = 0; nt < 8; ++nt) bv[nt] = bias[nt * 16 + col];
#pragma unroll
  for (int mt = 0; mt < 2; ++mt) {
    int rowbase = bm0 + w * 32 + mt * 16 + (lane >> 4) * 4;
#pragma unroll
    for (int reg = 0; reg < 4; ++reg) {
      int row = rowbase + reg;
      if (row >= n) continue;
#pragma unroll
      for (int nt = 0; nt < 8; ++nt) {
        float t = acc[mt][nt][reg] + bv[nt];
        out[(size_t)row * 128 + nt * 16 + col] = relu ? fmaxf(t, 0.f) : t;
      }
    }
  }
}

extern "C" void kernel_launch(void* const* d_in, const int* in_sizes, int n_in,
                              void* d_out, int out_size, void* d_ws, size_t ws_size,
                              hipStream_t stream) {
  const int D = 128;
  const int N = in_sizes[0] / D;
  const int E = in_sizes[7];

  const float* x  = (const float*)d_in[0];
  const float* W0 = (const float*)d_in[1];
  const float* b0 = (const float*)d_in[2];
  const float* W1 = (const float*)d_in[3];
  const float* b1 = (const float*)d_in[4];
  const float* W2 = (const float*)d_in[5];
  const float* b2 = (const float*)d_in[6];
  const int* src  = (const int*)d_in[7];
  const int* dst  = (const int*)d_in[8];
  float* out = (float*)d_out;

  char* p = (char*)d_ws;
  auto alloc = [&](size_t bytes) -> char* {
    char* r = p;
    p += (bytes + 15) & ~(size_t)15;
    return r;
  };
  float* invout = (float*)alloc((size_t)N * 4);
  float* invin  = (float*)alloc((size_t)N * 4);
  int* cntin  = (int*)alloc((size_t)N * 4);
  int* cntout = (int*)alloc((size_t)N * 4);
  int* offf = (int*)alloc((size_t)(N + 1) * 4);
  int* offb = (int*)alloc((size_t)(N + 1) * 4);
  int* rankf = (int*)alloc((size_t)E * 4);
  int* rankb = (int*)alloc((size_t)E * 4);
  int* lstf = (int*)alloc((size_t)E * 4);
  int* lstb = (int*)alloc((size_t)E * 4);
  unsigned* xbu = (unsigned*)alloc((size_t)N * 64 * 4);   // bf16x2 packed
  unsigned* fwdb = (unsigned*)alloc((size_t)N * 64 * 4);
  unsigned* bwdb = (unsigned*)alloc((size_t)N * 64 * 4);
  float* x1 = (float*)alloc((size_t)N * D * 4);
  unsigned* Wth[3], *Wtl[3];
  for (int l = 0; l < 3; ++l) {
    Wth[l] = (unsigned*)alloc((size_t)128 * 192 * 4);
    Wtl[l] = (unsigned*)alloc((size_t)128 * 192 * 4);
  }
  int nbScan = (N + 1 + 2047) / 2048;
  int* partA = (int*)alloc((size_t)(nbScan + 1) * 4);
  int* partB = (int*)alloc((size_t)(nbScan + 1) * 4);

  hipMemsetAsync(cntin, 0, (size_t)2 * N * 4, stream);  // cntin+cntout contiguous

  k_degrees<<<(E + 255) / 256, 256, 0, stream>>>(src, dst, cntin, cntout, rankf,
                                                 rankb, E);
  k_inv<<<(N + 255) / 256, 256, 0, stream>>>(cntin, cntout, invin, invout, N);
  k_scan_part<<<dim3(nbScan, 2), 256, 0, stream>>>(cntin, cntout, partA, partB, N);
  k_scan_tops<<<dim3(1, 2), 64, 0, stream>>>(partA, partB, nbScan);
  k_scan_out<<<dim3(nbScan, 2), 256, 0, stream>>>(cntin, cntout, partA, partB,
                                                  offf, offb, N);
  k_fill<<<(E + 255) / 256, 256, 0, stream>>>(src, dst, offf, offb, rankf, rankb,
                                              lstf, lstb, E);
  const float* Ws[3] = {W0, W1, W2};
  const float* bs[3] = {b0, b1, b2};
  for (int l = 0; l < 3; ++l)
    k_wconv<<<(128 * 192 + 255) / 256, 256, 0, stream>>>(Ws[l], Wth[l], Wtl[l]);

  int aggBlocks = (N * 64 + 255) / 256;   // one wave per node (x), dir in y
  int convBlocks = (N * 32 + 255) / 256;
  int gemmBlocks = (N + 127) / 128;
  for (int l = 0; l < 3; ++l) {
    const float* xc = (l == 0) ? x : ((l == 1) ? x1 : out);
    float* xo = (l == 0) ? x1 : out;
    k_conv<<<convBlocks, 256, 0, stream>>>(xc, xbu, N);
    // fwd[v] = sum_{s:(s,v)} x[s]*inv_out[s]; bwd[v] = sum_{d:(v,d)} x[d]*inv_in[d]
    k_agg2<<<dim3(aggBlocks, 2), 256, 0, stream>>>(
        (const uint4*)xbu, offf, lstf, invout, offb, lstb, invin,
        (uint4*)fwdb, (uint4*)bwdb, N);
    k_gemm<<<gemmBlocks, 256, 0, stream>>>(xbu, fwdb, bwdb, Wth[l], Wtl[l], bs[l],
                                           xo, N, (l < 2) ? 1 : 0);
  }
}